// Round 3
// baseline (376.730 us; speedup 1.0000x reference)
//
#include <hip/hip_runtime.h>

// 3x3 SAME conv + bias + ReLU, N=32, Cin=Cout=256, H=W=56, fp32 in/out.
// v3: implicit-GEMM bf16 MFMA with conv-specific LDS patch reuse:
//  - B: 6x58-pixel x 64ch patch staged once per channel-chunk; 9 taps read
//    shifted positions from LDS (no per-tap restaging).
//  - A: weights (bf16, repacked, L2-resident) loaded directly to registers.
//  - BM=128 x BN=224 (4 image rows), 4 waves, wave tile 64co x 112px.

typedef __attribute__((ext_vector_type(8))) short short8;
typedef __attribute__((ext_vector_type(4))) float f32x4;

#define CIN   256
#define HWS   3136      // 56*56
#define KTOT  2304      // CIN*9
#define WROWB 4608      // KTOT*2 bytes per weight row

__device__ __forceinline__ unsigned short f2bf(float f) {
  unsigned u = __builtin_bit_cast(unsigned, f);
  return (unsigned short)((u + 0x7fffu + ((u >> 16) & 1u)) >> 16);  // RNE
}

// Repack weights OIHW fp32 -> bf16 [co][tap*256+ci]
__global__ void wcvt_kernel(const float* __restrict__ w, unsigned short* __restrict__ wb) {
  int o = blockIdx.x * 256 + threadIdx.x;
  int co = o / KTOT;
  int rr = o - co * KTOT;
  int tap = rr >> 8;
  int ci = rr & 255;
  wb[o] = f2bf(w[co * KTOT + ci * 9 + tap]);
}

__global__ __launch_bounds__(256, 2) void conv_kernel(
    const float* __restrict__ x, const unsigned char* __restrict__ wb,
    const float* __restrict__ bias, float* __restrict__ out) {
  // B patch: 352 pixel-granules (6*58=348 used, padded to 352) x 128B
  __shared__ __align__(16) unsigned char ldsB[45056];

  const int bid = blockIdx.x;
  const int sw  = (bid & 7) * 112 + (bid >> 3);  // XCD-chunked, bijective (896=8*112)
  const int co0 = (sw & 1) * 128;
  const int pt  = sw >> 1;                        // pixel tile 0..447
  const int n_img = pt / 14;
  const int trow  = pt - n_img * 14;              // 4-row band 0..13
  const int ph0   = trow * 4;

  const int t    = threadIdx.x;
  const int lane = t & 63;
  const int wave = t >> 6;   // 0..3
  const int wm   = wave & 1;
  const int wn   = wave >> 1;
  const int rl   = lane & 15;
  const int kq   = lane >> 4;

  const float* xn = x + (size_t)n_img * (CIN * HWS);

  // A row base pointers (direct-from-global fragments)
  const unsigned char* aBase[4];
#pragma unroll
  for (int m = 0; m < 4; ++m)
    aBase[m] = wb + (size_t)(co0 + wm * 64 + m * 16 + rl) * WROWB + kq * 16;

  // B pixel-granule bases per n-frag (patch coords, pre-halo-shift)
  int ppb[7];
#pragma unroll
  for (int n = 0; n < 7; ++n) {
    int ptile = wn * 112 + n * 16 + rl;   // 0..223
    int pr = ptile / 56;
    int pc = ptile - pr * 56;
    ppb[n] = pr * 58 + pc;
  }

  f32x4 acc[4][7];
  const f32x4 zero4 = {0.f, 0.f, 0.f, 0.f};
#pragma unroll
  for (int m = 0; m < 4; ++m)
#pragma unroll
    for (int n = 0; n < 7; ++n) acc[m][n] = zero4;

  // staging lane split: 8 pixels x 8 channel-pairs per instruction
  const int ga = lane & 7;     // pixel within group
  const int gb = lane >> 3;    // channel-pair

  for (int cq = 0; cq < 4; ++cq) {
    const int c0 = cq * 64;
    __syncthreads();
    // ---- stage B patch: 352 granules x 64ch, once per channel-chunk ----
#pragma unroll
    for (int i = 0; i < 11; ++i) {
      const int gid = wave * 11 + i;        // 0..43
      const int pp  = gid * 8 + ga;         // granule 0..351
      const int hh  = pp / 58;
      const int ww  = pp - hh * 58;
      const int h   = ph0 + hh - 1;
      const int w   = ww - 1;
      const bool valid = ((unsigned)h < 56u) && ((unsigned)w < 56u);
      const int offpix = valid ? h * 56 + w : 0;
      const float* xp = xn + (size_t)(c0 + 2 * gb) * HWS + offpix;
      const unsigned swz   = (unsigned)((pp & 7) << 4);
      const unsigned gbase = (unsigned)(pp << 7);
#pragma unroll
      for (int q = 0; q < 4; ++q) {
        float f0 = xp[(size_t)(q * 16) * HWS];
        float f1 = xp[(size_t)(q * 16 + 1) * HWS];
        if (!valid) { f0 = 0.f; f1 = 0.f; }
        unsigned u = (unsigned)f2bf(f0) | ((unsigned)f2bf(f1) << 16);
        *(unsigned*)(ldsB + gbase + (((unsigned)(q * 32 + gb * 4)) ^ swz)) = u;
      }
    }
    __syncthreads();

    // ---- 9 taps, barrier-free: direct A loads + LDS B reads + MFMA ----
#pragma unroll
    for (int tap = 0; tap < 9; ++tap) {
      const int koff = tap * 512 + cq * 128;
      const int kh   = tap / 3;
      const int tdel = kh * 58 + (tap - kh * 3);
      short8 a[2][4], b[2][7];
#pragma unroll
      for (int ks = 0; ks < 2; ++ks) {
#pragma unroll
        for (int m = 0; m < 4; ++m)
          a[ks][m] = *(const short8*)(aBase[m] + koff + ks * 64);
#pragma unroll
        for (int n = 0; n < 7; ++n) {
          const int pp = ppb[n] + tdel;
          const unsigned addr = ((unsigned)pp << 7) +
              (((unsigned)(kq * 16 + ks * 64)) ^ ((unsigned)((pp & 7) << 4)));
          b[ks][n] = *(const short8*)(ldsB + addr);
        }
      }
#pragma unroll
      for (int ks = 0; ks < 2; ++ks)
#pragma unroll
        for (int m = 0; m < 4; ++m)
#pragma unroll
          for (int n = 0; n < 7; ++n)
            acc[m][n] = __builtin_amdgcn_mfma_f32_16x16x32_bf16(a[ks][m], b[ks][n], acc[m][n], 0, 0, 0);
    }
  }

  // ---- epilogue: bias + ReLU. C/D map: col=lane&15, row=(lane>>4)*4+j ----
  {
    float br[4][4];
#pragma unroll
    for (int m = 0; m < 4; ++m)
#pragma unroll
      for (int j = 0; j < 4; ++j)
        br[m][j] = bias[co0 + wm * 64 + m * 16 + kq * 4 + j];

    float* outn = out + (size_t)n_img * (CIN * HWS);
#pragma unroll
    for (int m = 0; m < 4; ++m) {
      const int row = co0 + wm * 64 + m * 16 + kq * 4;
#pragma unroll
      for (int n = 0; n < 7; ++n) {
        const int col = trow * 224 + wn * 112 + n * 16 + rl;
        float* po = outn + (size_t)row * HWS + col;
#pragma unroll
        for (int j = 0; j < 4; ++j) {
          float v = acc[m][n][j] + br[m][j];
          po[(size_t)j * HWS] = fmaxf(v, 0.f);
        }
      }
    }
  }
}

extern "C" void kernel_launch(void* const* d_in, const int* in_sizes, int n_in,
                              void* d_out, int out_size, void* d_ws, size_t ws_size,
                              hipStream_t stream) {
  const float* x    = (const float*)d_in[0];
  const float* w    = (const float*)d_in[1];
  const float* bias = (const float*)d_in[2];
  float* out        = (float*)d_out;
  unsigned short* wb = (unsigned short*)d_ws;  // 1,179,648 B

  hipLaunchKernelGGL(wcvt_kernel, dim3(2304), dim3(256), 0, stream, w, wb);
  hipLaunchKernelGGL(conv_kernel, dim3(896), dim3(256), 0, stream,
                     x, (const unsigned char*)d_ws, bias, out);
}

// Round 4
// 361.604 us; speedup vs baseline: 1.0418x; 1.0418x over previous
//
#include <hip/hip_runtime.h>

// 3x3 SAME conv + bias + ReLU, N=32, Cin=Cout=256, H=W=56, fp32 in/out.
// v4: implicit-GEMM bf16 MFMA.
//  - B: 6x58-pixel x 64ch patch in LDS, staged once per channel-chunk;
//    9 taps read shifted positions (barrier-free within the chunk).
//  - A: weights bf16 via async global_load_lds, per-tap 32KB double-buffer
//    (prefetch issued one full compute phase ahead).
//  - BM=256 (all co) x BN=224 (4 rows), 512 thr / 8 waves, wave 64co x 112px.

#define GLOBAL_AS __attribute__((address_space(1)))
#define LDS_AS __attribute__((address_space(3)))

typedef __attribute__((ext_vector_type(8))) short short8;
typedef __attribute__((ext_vector_type(4))) float f32x4;

#define CIN   256
#define HWS   3136      // 56*56
#define KTOT  2304      // CIN*9
#define WROWB 4608      // KTOT*2 bytes per weight row

__device__ __forceinline__ unsigned short f2bf(float f) {
  unsigned u = __builtin_bit_cast(unsigned, f);
  return (unsigned short)((u + 0x7fffu + ((u >> 16) & 1u)) >> 16);  // RNE
}

// Repack weights OIHW fp32 -> bf16 [co][tap*256+ci]
__global__ void wcvt_kernel(const float* __restrict__ w, unsigned short* __restrict__ wb) {
  int o = blockIdx.x * 256 + threadIdx.x;
  int co = o / KTOT;
  int rr = o - co * KTOT;
  int tap = rr >> 8;
  int ci = rr & 255;
  wb[o] = f2bf(w[co * KTOT + ci * 9 + tap]);
}

__global__ __launch_bounds__(512, 2) void conv_kernel(
    const float* __restrict__ x, const unsigned char* __restrict__ wb,
    const float* __restrict__ bias, float* __restrict__ out) {
  // LDS: A dbuf 2x32768 at 0; B patch 45056 at 65536. Total 110592.
  __shared__ __align__(16) unsigned char smem[110592];

  const int bid   = blockIdx.x;
  const int tile  = (bid & 7) * 56 + (bid >> 3);  // XCD-chunked, bijective (448=8*56)
  const int n_img = tile / 14;
  const int trow  = tile - n_img * 14;            // 4-row band 0..13
  const int ph0   = trow * 4;

  const int t    = threadIdx.x;
  const int lane = t & 63;
  const int wave = t >> 6;     // 0..7
  const int wm   = wave & 3;   // co quarter (64 rows)
  const int wn   = wave >> 2;  // px half (112 cols)
  const int rl   = lane & 15;
  const int kq   = lane >> 4;
  const unsigned swzk = (unsigned)((rl & 7) << 4);

  const float* xn = x + (size_t)n_img * (CIN * HWS);
  unsigned char* ldsB = smem + 65536;

  // B pixel-granule bases (patch coords, pre-halo-shift)
  int ppb[7];
#pragma unroll
  for (int n = 0; n < 7; ++n) {
    int ptile = wn * 112 + n * 16 + rl;   // 0..223
    int pr = ptile / 56;
    ppb[n] = pr * 58 + (ptile - pr * 56);
  }

  f32x4 acc[4][7];
  const f32x4 zero4 = {0.f, 0.f, 0.f, 0.f};
#pragma unroll
  for (int m = 0; m < 4; ++m)
#pragma unroll
    for (int n = 0; n < 7; ++n) acc[m][n] = zero4;

  // patch staging split: thread -> (pixel-granule group, channel-pair)
  const int ppid = t >> 3;   // 0..63
  const int gb   = t & 7;    // channel-pair selector

  auto stagePatch = [&](int cq) {
    const int c0 = cq * 64;
#pragma unroll
    for (int i = 0; i < 6; ++i) {
      const int pp = i * 64 + ppid;       // granule 0..383 (352 used)
      if (pp < 352) {
        const int hh = pp / 58;
        const int ww = pp - hh * 58;
        const int h  = ph0 + hh - 1;
        const int w  = ww - 1;
        const bool valid = ((unsigned)h < 56u) && ((unsigned)w < 56u);
        const int offpix = valid ? h * 56 + w : 0;
        const float* xp = xn + (size_t)(c0 + 2 * gb) * HWS + offpix;
        const unsigned swz = (unsigned)((pp & 7) << 4);
        unsigned char* gptr = ldsB + ((unsigned)pp << 7);
#pragma unroll
        for (int q = 0; q < 4; ++q) {
          float f0 = xp[(size_t)(q * 16) * HWS];
          float f1 = xp[(size_t)(q * 16 + 1) * HWS];
          if (!valid) { f0 = 0.f; f1 = 0.f; }
          unsigned u = (unsigned)f2bf(f0) | ((unsigned)f2bf(f1) << 16);
          *(unsigned*)(gptr + (((unsigned)(q * 32 + gb * 4)) ^ swz)) = u;
        }
      }
    }
  };

  // A stage: 256co x 64k bf16 (32KB) via global_load_lds, pre-swizzled source
  auto stageAk = [&](int koff, int buf) {
#pragma unroll
    for (int i = 0; i < 4; ++i) {
      unsigned o   = (unsigned)(i * 8192 + wave * 1024 + lane * 16);  // linear LDS byte
      unsigned row = o >> 7;     // co 0..255 (128B per row)
      unsigned sb  = o & 127;
      const unsigned char* g = wb + (size_t)row * WROWB + (unsigned)koff
                              + (sb ^ ((row & 7) << 4));
      unsigned char* l = smem + buf * 32768 + i * 8192 + wave * 1024;  // wave-uniform
      __builtin_amdgcn_global_load_lds((const GLOBAL_AS unsigned int*)g,
                                       (LDS_AS unsigned int*)l, 16, 0, 0);
    }
  };

  // ---- prologue ----
  stagePatch(0);
  stageAk(0, 0);
  __syncthreads();

  int buf = 0;
  for (int cq = 0; cq < 4; ++cq) {
#pragma unroll
    for (int tap = 0; tap < 9; ++tap) {
      // prefetch next A tile into the other buffer (issued before compute)
      if (!(cq == 3 && tap == 8)) {
        const int ntap = (tap == 8) ? 0 : tap + 1;
        const int ncq  = (tap == 8) ? cq + 1 : cq;
        stageAk(ntap * 512 + ncq * 128, buf ^ 1);
      }
      // compute tap from buf (A) + patch (B)
      {
        const unsigned char* bA = smem + buf * 32768;
        const int kh   = tap / 3;
        const int tdel = kh * 58 + (tap - kh * 3);
        short8 a[2][4], b[2][7];
#pragma unroll
        for (int ks = 0; ks < 2; ++ks) {
          const unsigned kb = (unsigned)(kq * 16 + ks * 64);
#pragma unroll
          for (int m = 0; m < 4; ++m) {
            const int ar = wm * 64 + m * 16 + rl;
            a[ks][m] = *(const short8*)(bA + ar * 128 + (kb ^ swzk));
          }
#pragma unroll
          for (int n = 0; n < 7; ++n) {
            const int pp = ppb[n] + tdel;
            b[ks][n] = *(const short8*)(ldsB + ((unsigned)pp << 7)
                        + (kb ^ ((unsigned)((pp & 7) << 4))));
          }
        }
#pragma unroll
        for (int ks = 0; ks < 2; ++ks)
#pragma unroll
          for (int m = 0; m < 4; ++m)
#pragma unroll
            for (int n = 0; n < 7; ++n)
              acc[m][n] = __builtin_amdgcn_mfma_f32_16x16x32_bf16(a[ks][m], b[ks][n], acc[m][n], 0, 0, 0);
      }
      __syncthreads();
      buf ^= 1;
    }
    if (cq < 3) {
      stagePatch(cq + 1);
      __syncthreads();
    }
  }

  // ---- epilogue: bias + ReLU. C/D map: col=lane&15, row=(lane>>4)*4+j ----
  {
    float br[4][4];
#pragma unroll
    for (int m = 0; m < 4; ++m)
#pragma unroll
      for (int j = 0; j < 4; ++j)
        br[m][j] = bias[wm * 64 + m * 16 + kq * 4 + j];

    float* outn = out + (size_t)n_img * (CIN * HWS);
#pragma unroll
    for (int m = 0; m < 4; ++m) {
      const int row = wm * 64 + m * 16 + kq * 4;
#pragma unroll
      for (int n = 0; n < 7; ++n) {
        const int col = trow * 224 + wn * 112 + n * 16 + rl;
        float* po = outn + (size_t)row * HWS + col;
#pragma unroll
        for (int j = 0; j < 4; ++j) {
          float v = acc[m][n][j] + br[m][j];
          po[(size_t)j * HWS] = fmaxf(v, 0.f);
        }
      }
    }
  }
}

extern "C" void kernel_launch(void* const* d_in, const int* in_sizes, int n_in,
                              void* d_out, int out_size, void* d_ws, size_t ws_size,
                              hipStream_t stream) {
  const float* x    = (const float*)d_in[0];
  const float* w    = (const float*)d_in[1];
  const float* bias = (const float*)d_in[2];
  float* out        = (float*)d_out;
  unsigned short* wb = (unsigned short*)d_ws;  // 1,179,648 B

  hipLaunchKernelGGL(wcvt_kernel, dim3(2304), dim3(256), 0, stream, w, wb);
  hipLaunchKernelGGL(conv_kernel, dim3(448), dim3(512), 0, stream,
                     x, (const unsigned char*)d_ws, bias, out);
}